// Round 3
// baseline (201.346 us; speedup 1.0000x reference)
//
#include <hip/hip_runtime.h>
#include <hip/hip_cooperative_groups.h>
#include <math.h>

namespace cg = cooperative_groups;

// Problem constants (must match reference)
#define NB   2        // images
#define NP   1024     // proposals per image
#define NC   61       // classes incl. background
#define NFG  60       // foreground classes
#define KTOP 100      // detections per image
#define CAP  20480    // candidate buffer per image (>= 19*1024 worst-case valid)
#define MAXSEL 4096   // top-k selection buffer
#define GRID (NB*NFG) // 120 blocks, one wave each

typedef unsigned long long u64;

__device__ __forceinline__ float clampf(float x, float lo, float hi) {
  return fminf(fmaxf(x, lo), hi);
}

// One fused cooperative kernel:
//  P1: per-row softmax, scores written TRANSPOSED [b][cls-1][n] (coalesced P2 reads)
//  P2: per-(image,class) wave: ballot-compact, u64 rank sort, register-resident
//      boxes, precomputed suppression-row bitmasks (dependence-free, pipelined),
//      cheap sequential greedy (shfl+or), single atomic range reservation.
//  P3: per-image wave top-100: LDS histogram + wave suffix-scan threshold,
//      u64-key exact rank sort (score desc, flat asc), direct scatter to out.
__global__ void __launch_bounds__(64)
fused_kernel(const float* __restrict__ logits,
             const float* __restrict__ deltas,
             const float* __restrict__ props,
             float* __restrict__ scores_t,
             float* __restrict__ cscore,
             int* __restrict__ cflat,
             int* __restrict__ clabel,
             float* __restrict__ cbox,
             int* __restrict__ ccnt,
             float* __restrict__ out) {
  const float SCALE_CLAMP = 4.135166556742356f;  // float(log(1000/16))
  int lane = threadIdx.x;
  u64 lt = (1ull << lane) - 1ull;

  // LDS union: P2 uses ukey/skey/sbox (32KB+16KB), P3 reuses as hist/sel (~50KB)
  __shared__ __align__(16) unsigned char smem[50176];
  u64* ukey = (u64*)smem;                       //  8KB  (1024 u64)
  u64* skey = (u64*)(smem + 8192);              //  8KB
  float (*sbox)[4] = (float(*)[4])(smem + 16384); // 16KB (fallback path only)

  cg::grid_group grid = cg::this_grid();

  // ---------------- P1: softmax + transpose ----------------
  if (blockIdx.x == 0 && lane < NB) ccnt[lane] = 0;
  for (int row = blockIdx.x; row < NB * NP; row += GRID) {
    float x = (lane < NC) ? logits[(size_t)row * NC + lane] : -INFINITY;
    float m = x;
    #pragma unroll
    for (int o = 32; o; o >>= 1) m = fmaxf(m, __shfl_xor(m, o, 64));
    float e = (lane < NC) ? expf(x - m) : 0.0f;
    float s = e;
    #pragma unroll
    for (int o = 32; o; o >>= 1) s += __shfl_xor(s, o, 64);
    if (lane >= 1 && lane < NC)
      scores_t[(size_t)((row >> 10) * NFG + (lane - 1)) * NP + (row & (NP - 1))] = e / s;
  }
  grid.sync();

  // ---------------- P2: per-class NMS ----------------
  int b = blockIdx.x / NFG, j = blockIdx.x % NFG, cls = j + 1;
  {
    const float* scol = scores_t + (size_t)(b * NFG + j) * NP;
    float sc[16];
    #pragma unroll
    for (int c = 0; c < 16; ++c) sc[c] = scol[c * 64 + lane];  // coalesced
    int nv = 0;
    #pragma unroll
    for (int c = 0; c < 16; ++c) {
      bool pred = sc[c] > 0.05f;
      u64 m = __ballot(pred);
      if (pred)
        ukey[nv + __popcll(m & lt)] =
            ((u64)__float_as_uint(sc[c]) << 32) | (unsigned)(NP - 1 - (c * 64 + lane));
      nv += (int)__popcll(m);
    }
    __syncthreads();
    int chunks = (nv + 63) >> 6;

    // exact rank sort desc (keys unique: score bits | complemented index)
    for (int c = 0; c < chunks; ++c) {
      int e = c * 64 + lane;
      if (e < nv) {
        u64 ke = ukey[e];
        int r = 0;
        for (int m2 = 0; m2 < nv; ++m2) r += (ukey[m2] > ke) ? 1 : 0;
        skey[r] = ke;
      }
    }
    __syncthreads();

    if (nv > 0 && nv <= 256) {
      // ---- register fast path (chunks <= 4) ----
      float x0[4], y0[4], x1[4], y1[4], ar[4], scr[4];
      #pragma unroll
      for (int c = 0; c < 4; ++c) {
        x0[c] = y0[c] = x1[c] = y1[c] = 1e30f; ar[c] = 0.0f; scr[c] = 0.0f;
        int p = c * 64 + lane;
        if (c < chunks && p < nv) {
          u64 k = skey[p];
          scr[c] = __uint_as_float((unsigned)(k >> 32));
          int n = NP - 1 - (int)(k & 0xFFFFull);
          int row = b * NP + n;
          float4 pr = *(const float4*)(props + (size_t)row * 4);
          float w = pr.z - pr.x, h = pr.w - pr.y;
          float cx = pr.x + 0.5f * w, cy = pr.y + 0.5f * h;
          float4 dd = *(const float4*)(deltas + (size_t)row * (NC * 4) + cls * 4);
          float dx = dd.x / 10.0f, dy = dd.y / 10.0f;
          float dw = fminf(dd.z / 5.0f, SCALE_CLAMP);
          float dh = fminf(dd.w / 5.0f, SCALE_CLAMP);
          float pcx = dx * w + cx, pcy = dy * h + cy;
          float pw = expf(dw) * w, ph = expf(dh) * h;
          x0[c] = clampf(pcx - 0.5f * pw, 0.0f, 1024.0f);
          y0[c] = clampf(pcy - 0.5f * ph, 0.0f, 1024.0f);
          x1[c] = clampf(pcx + 0.5f * pw, 0.0f, 1024.0f);
          y1[c] = clampf(pcy + 0.5f * ph, 0.0f, 1024.0f);
          ar[c] = (x1[c] - x0[c]) * (y1[c] - y0[c]);
        }
      }

      // precompute suppression rows (independent iterations -> pipelined)
      u64 rows_r[4][4];  // [chunk of i][target chunk], owned by lane (i&63)
      #pragma unroll
      for (int a = 0; a < 4; ++a)
        #pragma unroll
        for (int c2 = 0; c2 < 4; ++c2) rows_r[a][c2] = 0;

      for (int i = 0; i < nv; ++i) {
        int ci = i >> 6, bi = i & 63;
        float t0 = x0[0], t1 = y0[0], t2 = x1[0], t3 = y1[0], ta = ar[0];
        #pragma unroll
        for (int c = 1; c < 4; ++c)
          if (ci == c) { t0 = x0[c]; t1 = y0[c]; t2 = x1[c]; t3 = y1[c]; ta = ar[c]; }
        float ix0 = __shfl(t0, bi), iy0 = __shfl(t1, bi);
        float ix1 = __shfl(t2, bi), iy1 = __shfl(t3, bi);
        float ia  = __shfl(ta, bi);
        #pragma unroll
        for (int c2 = 0; c2 < 4; ++c2) if (c2 < chunks) {
          float iw = fmaxf(fminf(ix1, x1[c2]) - fmaxf(ix0, x0[c2]), 0.0f);
          float ih = fmaxf(fminf(iy1, y1[c2]) - fmaxf(iy0, y0[c2]), 0.0f);
          float inter = iw * ih;
          float iou = inter / (ia + ar[c2] - inter + 1e-9f);
          u64 mb = __ballot(iou > 0.5f);  // bits over target entries c2*64+lane
          #pragma unroll
          for (int a = 0; a < 4; ++a)
            if (a == ci && lane == bi) rows_r[a][c2] = mb;
        }
      }

      // sequential greedy: wave-uniform masks, shfl-broadcast rows
      u64 supm[4] = {0, 0, 0, 0}, keptm[4] = {0, 0, 0, 0};
      for (int i = 0; i < nv; ++i) {
        int ci = i >> 6, bi = i & 63;
        u64 sv = supm[0];
        #pragma unroll
        for (int c = 1; c < 4; ++c) if (ci == c) sv = supm[c];
        if ((sv >> bi) & 1ull) continue;   // uniform branch
        #pragma unroll
        for (int c = 0; c < 4; ++c) if (ci == c) keptm[c] |= (1ull << bi);
        #pragma unroll
        for (int c2 = 0; c2 < 4; ++c2) if (c2 < chunks) {
          u64 rr = rows_r[0][c2];
          #pragma unroll
          for (int c = 1; c < 4; ++c) if (ci == c) rr = rows_r[c][c2];
          rr = __shfl(rr, bi);
          supm[c2] |= rr;
        }
      }

      // write-out: one atomic per block
      int total = 0;
      #pragma unroll
      for (int c = 0; c < 4; ++c) total += (int)__popcll(keptm[c]);
      int basei = 0;
      if (lane == 0 && total > 0) basei = atomicAdd(&ccnt[b], total);
      basei = __shfl(basei, 0);
      int prior = 0;
      #pragma unroll
      for (int c = 0; c < 4; ++c) if (c < chunks) {
        u64 mk = keptm[c];
        if ((mk >> lane) & 1ull) {
          int slot = basei + prior + (int)__popcll(mk & lt);
          if (slot < CAP) {
            int g = b * CAP + slot;
            cscore[g] = scr[c];
            cflat[g]  = j * NP + (c * 64 + lane);
            clabel[g] = cls;
            float4 bb; bb.x = x0[c]; bb.y = y0[c]; bb.z = x1[c]; bb.w = y1[c];
            *(float4*)(cbox + (size_t)g * 4) = bb;
          }
        }
        prior += (int)__popcll(mk);
      }
    } else if (nv > 256) {
      // ---- LDS fallback (rare; R2-verified structure) ----
      for (int c = 0; c < chunks; ++c) {
        int p = c * 64 + lane;
        if (p < nv) {
          u64 k = skey[p];
          int n = NP - 1 - (int)(k & 0xFFFFull);
          int row = b * NP + n;
          float4 pr = *(const float4*)(props + (size_t)row * 4);
          float w = pr.z - pr.x, h = pr.w - pr.y;
          float cx = pr.x + 0.5f * w, cy = pr.y + 0.5f * h;
          float4 dd = *(const float4*)(deltas + (size_t)row * (NC * 4) + cls * 4);
          float dx = dd.x / 10.0f, dy = dd.y / 10.0f;
          float dw = fminf(dd.z / 5.0f, SCALE_CLAMP);
          float dh = fminf(dd.w / 5.0f, SCALE_CLAMP);
          float pcx = dx * w + cx, pcy = dy * h + cy;
          float pw = expf(dw) * w, ph = expf(dh) * h;
          sbox[p][0] = clampf(pcx - 0.5f * pw, 0.0f, 1024.0f);
          sbox[p][1] = clampf(pcy - 0.5f * ph, 0.0f, 1024.0f);
          sbox[p][2] = clampf(pcx + 0.5f * pw, 0.0f, 1024.0f);
          sbox[p][3] = clampf(pcy + 0.5f * ph, 0.0f, 1024.0f);
        }
      }
      __syncthreads();
      unsigned int supbits = 0, keptbits = 0;
      for (int i = 0; i < nv; ++i) {
        int ci = i >> 6, bi = i & 63;
        u64 supmask = __ballot((supbits >> ci) & 1u);
        if ((supmask >> bi) & 1ull) continue;
        keptbits |= ((lane == bi) ? 1u : 0u) << ci;
        float bx1 = sbox[i][0], by1 = sbox[i][1], bx2 = sbox[i][2], by2 = sbox[i][3];
        float ai = (bx2 - bx1) * (by2 - by1);
        for (int c = 0; c < chunks; ++c) {
          int p = c * 64 + lane;
          float t1 = sbox[p][0], t2 = sbox[p][1], t3 = sbox[p][2], t4 = sbox[p][3];
          float at = (t3 - t1) * (t4 - t2);
          float iw = fmaxf(fminf(bx2, t3) - fmaxf(bx1, t1), 0.0f);
          float ih = fmaxf(fminf(by2, t4) - fmaxf(by1, t2), 0.0f);
          float inter = iw * ih;
          float iou = inter / (ai + at - inter + 1e-9f);
          bool s = (p < nv) && (iou > 0.5f);
          supbits |= (s ? 1u : 0u) << c;
        }
      }
      int total = 0;
      for (int c = 0; c < chunks; ++c)
        total += (int)__popcll(__ballot((keptbits >> c) & 1u));
      int basei = 0;
      if (lane == 0 && total > 0) basei = atomicAdd(&ccnt[b], total);
      basei = __shfl(basei, 0);
      int prior = 0;
      for (int c = 0; c < chunks; ++c) {
        u64 mask = __ballot((keptbits >> c) & 1u);
        if ((keptbits >> c) & 1u) {
          int slot = basei + prior + (int)__popcll(mask & lt);
          int p = c * 64 + lane;
          if (slot < CAP) {
            int g = b * CAP + slot;
            cscore[g] = __uint_as_float((unsigned)(skey[p] >> 32));
            cflat[g]  = j * NP + p;
            clabel[g] = cls;
            float4 bb; bb.x = sbox[p][0]; bb.y = sbox[p][1]; bb.z = sbox[p][2]; bb.w = sbox[p][3];
            *(float4*)(cbox + (size_t)g * 4) = bb;
          }
        }
        prior += (int)__popcll(mask);
      }
    }
  }
  grid.sync();

  // ---------------- P3: per-image top-100 ----------------
  if (blockIdx.x < NB) {
    int bb = blockIdx.x;
    int cnt = ccnt[bb]; if (cnt > CAP) cnt = CAP;
    const float* cs = cscore + (size_t)bb * CAP;
    const int* cf = cflat + (size_t)bb * CAP;
    int* hist = (int*)smem;                        // 1KB
    u64* sel_k = (u64*)(smem + 1024);              // 32KB
    int* sel_i = (int*)(smem + 1024 + 8 * MAXSEL); // 16KB

    for (int i = lane; i < 256; i += 64) hist[i] = 0;
    __syncthreads();
    for (int i = lane; i < cnt; i += 64) {
      int bin = (int)(cs[i] * 256.0f);
      bin = bin < 0 ? 0 : (bin > 255 ? 255 : bin);
      atomicAdd(&hist[bin], 1);
    }
    __syncthreads();

    // threshold bin: largest t with |{score-bin >= t}| >= K (wave suffix scan)
    int c0 = hist[lane * 4 + 0], c1 = hist[lane * 4 + 1];
    int c2 = hist[lane * 4 + 2], c3 = hist[lane * 4 + 3];
    int sl = c0 + c1 + c2 + c3;
    int suf = sl;
    #pragma unroll
    for (int off = 1; off < 64; off <<= 1) {
      int idx = lane + off;
      int v = __shfl(suf, idx < 64 ? idx : 63, 64);
      suf += (idx < 64) ? v : 0;
    }
    int basec = suf - sl;
    int f3 = basec + c3, f2 = f3 + c2, f1 = f2 + c1, f0 = f1 + c0;
    int best = -1;
    if (f3 >= KTOP) best = lane * 4 + 3;
    else if (f2 >= KTOP) best = lane * 4 + 2;
    else if (f1 >= KTOP) best = lane * 4 + 1;
    else if (f0 >= KTOP) best = lane * 4 + 0;
    #pragma unroll
    for (int off = 32; off; off >>= 1) {
      int o = __shfl_xor(best, off, 64);
      best = best > o ? best : o;
    }
    int thr = best < 0 ? 0 : best;

    // select candidates in bins >= thr (superset of top-K)
    int nsel = 0;
    for (int i0 = 0; i0 < cnt; i0 += 64) {
      int i = i0 + lane;
      bool pred = false; u64 key = 0;
      if (i < cnt) {
        float s_ = cs[i];
        int bin = (int)(s_ * 256.0f);
        bin = bin < 0 ? 0 : (bin > 255 ? 255 : bin);
        if (bin >= thr) {
          pred = true;
          // (score desc, flat asc): flat < 61440 fits 16 bits, complemented
          key = ((u64)__float_as_uint(s_) << 32) | (unsigned)(65535 - cf[i]);
        }
      }
      u64 m = __ballot(pred);
      if (pred) {
        int pos = nsel + (int)__popcll(m & lt);
        if (pos < MAXSEL) { sel_k[pos] = key; sel_i[pos] = i; }
      }
      nsel += (int)__popcll(m);
    }
    if (nsel > MAXSEL) nsel = MAXSEL;
    __syncthreads();

    // exact rank sort + direct scatter
    for (int e = lane; e < nsel; e += 64) {
      u64 ke = sel_k[e];
      int r = 0;
      for (int m2 = 0; m2 < nsel; ++m2) r += (sel_k[m2] > ke) ? 1 : 0;
      if (r < KTOP) {
        int ci = sel_i[e];
        float4 bx = *(const float4*)(cbox + (size_t)(bb * CAP + ci) * 4);
        float* det = out + (size_t)(bb * KTOP + r) * 5;
        det[0] = bx.x; det[1] = bx.y; det[2] = bx.z; det[3] = bx.w;
        det[4] = __uint_as_float((unsigned)(ke >> 32));
        out[NB * KTOP * 5 + bb * KTOP + r] = (float)clabel[bb * CAP + ci];
      }
    }
    for (int k = nsel + lane; k < KTOP; k += 64) {
      float* det = out + (size_t)(bb * KTOP + k) * 5;
      det[0] = det[1] = det[2] = det[3] = 0.0f;
      det[4] = 0.0f;
      out[NB * KTOP * 5 + bb * KTOP + k] = 1.0f;  // zero-pad ties -> label 1
    }
  }
}

// ---------------------------------------------------------------------------
extern "C" void kernel_launch(void* const* d_in, const int* in_sizes, int n_in,
                              void* d_out, int out_size, void* d_ws, size_t ws_size,
                              hipStream_t stream) {
  (void)in_sizes; (void)n_in; (void)out_size; (void)ws_size;
  const float* logits = (const float*)d_in[0];   // [B*N, C]
  const float* deltas = (const float*)d_in[1];   // [B*N, C*4]
  const float* props  = (const float*)d_in[2];   // [B, N, 4]
  float* out = (float*)d_out;                    // dets [B,K,5] then labels [B,K]

  // workspace layout (float elements), total ~1.64 MB
  float* wf       = (float*)d_ws;
  float* scores_t = wf;                                  // [0, 122880)
  float* cscore   = wf + 122880;                         // NB*CAP = 40960
  float* cbox     = wf + 163840;                         // NB*CAP*4 = 163840 (16B-aligned)
  int*   cflat    = (int*)(wf + 327680);                 // 40960
  int*   clabel   = (int*)(wf + 368640);                 // 40960
  int*   ccnt     = (int*)(wf + 409600);                 // 2

  void* args[10] = {(void*)&logits, (void*)&deltas, (void*)&props,
                    (void*)&scores_t, (void*)&cscore, (void*)&cflat,
                    (void*)&clabel, (void*)&cbox, (void*)&ccnt, (void*)&out};
  hipLaunchCooperativeKernel((const void*)fused_kernel, dim3(GRID), dim3(64),
                             args, 0, stream);
}

// Round 5
// 163.784 us; speedup vs baseline: 1.2293x; 1.2293x over previous
//
#include <hip/hip_runtime.h>
#include <math.h>

// Problem constants (must match reference)
#define NB   2        // images
#define NP   1024     // proposals per image
#define NC   61       // classes incl. background
#define NFG  60       // foreground classes
#define KTOP 100      // detections per image
#define CAP  20480    // candidate buffer per image
#define MAXSEL 4096   // top-k selection buffer

typedef unsigned long long u64;

__device__ __forceinline__ float clampf(float x, float lo, float hi) {
  return fminf(fmaxf(x, lo), hi);
}

// ---------------------------------------------------------------------------
// K1: softmax + transpose. 128 blocks x 256 threads, 16 rows per block.
// Writes scores_t[b][cls-1][n] with coalesced 64B chunks via an LDS tile
// (R3's scatter version caused 4 MB of write-allocate traffic; this is 491 KB).
// ---------------------------------------------------------------------------
__global__ void __launch_bounds__(256)
softmax_t_kernel(const float* __restrict__ logits,
                 float* __restrict__ scores_t,
                 int* __restrict__ ccnt) {
  if (blockIdx.x == 0 && threadIdx.x < NB) ccnt[threadIdx.x] = 0;
  int b = blockIdx.x >> 6;          // 64 blocks per image
  int k = blockIdx.x & 63;          // tile (16 rows) within image
  int wave = threadIdx.x >> 6, lane = threadIdx.x & 63;
  __shared__ float p[16][65];       // +pad: phase-B reads hit distinct banks

  // phase A: 4 waves x 4 rows each, wave-shfl softmax
  for (int rr = 0; rr < 4; ++rr) {
    int r = wave * 4 + rr;
    int row = b * NP + k * 16 + r;
    float x = (lane < NC) ? logits[(size_t)row * NC + lane] : -INFINITY;
    float m = x;
    #pragma unroll
    for (int o = 32; o; o >>= 1) m = fmaxf(m, __shfl_xor(m, o, 64));
    float e = (lane < NC) ? expf(x - m) : 0.0f;
    float s = e;
    #pragma unroll
    for (int o = 32; o; o >>= 1) s += __shfl_xor(s, o, 64);
    if (lane >= 1 && lane < NC) p[r][lane - 1] = e / s;   // fg classes only
  }
  __syncthreads();

  // phase B: transposed coalesced write. idx = j*16 + r: every 16 consecutive
  // threads write one 64B contiguous chunk of class j's column.
  for (int idx = threadIdx.x; idx < NFG * 16; idx += 256) {
    int j = idx >> 4;
    int r = idx & 15;
    scores_t[(size_t)(b * NFG + j) * NP + k * 16 + r] = p[r][j];
  }
}

// ---------------------------------------------------------------------------
// K2: ONE WAVE per (image, fg class). Coalesced score-column read,
// ballot-compact, u64 rank sort, register-resident boxes, precomputed
// suppression-row bitmasks, cheap sequential greedy, one atomic per block.
// (Structure validated in R3; only the score source changed to scores_t.)
// ---------------------------------------------------------------------------
__global__ void __launch_bounds__(64)
nms_kernel(const float* __restrict__ scores_t,
           const float* __restrict__ deltas,
           const float* __restrict__ props,
           float* __restrict__ cscore,
           int* __restrict__ cflat,
           int* __restrict__ clabel,
           float* __restrict__ cbox,
           int* __restrict__ ccnt) {
  const float SCALE_CLAMP = 4.135166556742356f;  // float(log(1000/16))
  int b = blockIdx.x / NFG, j = blockIdx.x % NFG, cls = j + 1;
  int lane = threadIdx.x;
  u64 lt = (1ull << lane) - 1ull;

  __shared__ u64 ukey[NP];
  __shared__ u64 skey[NP];
  __shared__ float sbox[NP][4];     // fallback path only

  // 1) coalesced score loads + ballot compaction
  const float* scol = scores_t + (size_t)(b * NFG + j) * NP;
  float sc[16];
  #pragma unroll
  for (int c = 0; c < 16; ++c) sc[c] = scol[c * 64 + lane];
  int nv = 0;
  #pragma unroll
  for (int c = 0; c < 16; ++c) {
    bool pred = sc[c] > 0.05f;
    u64 m = __ballot(pred);
    if (pred)
      ukey[nv + __popcll(m & lt)] =
          ((u64)__float_as_uint(sc[c]) << 32) | (unsigned)(NP - 1 - (c * 64 + lane));
    nv += (int)__popcll(m);
  }
  __syncthreads();
  int chunks = (nv + 63) >> 6;

  // 2) exact rank sort desc (keys unique: score bits | complemented index)
  for (int c = 0; c < chunks; ++c) {
    int e = c * 64 + lane;
    if (e < nv) {
      u64 ke = ukey[e];
      int r = 0;
      for (int m2 = 0; m2 < nv; ++m2) r += (ukey[m2] > ke) ? 1 : 0;
      skey[r] = ke;
    }
  }
  __syncthreads();

  if (nv > 0 && nv <= 256) {
    // ---- register fast path (chunks <= 4) ----
    float x0[4], y0[4], x1[4], y1[4], ar[4], scr[4];
    #pragma unroll
    for (int c = 0; c < 4; ++c) {
      x0[c] = y0[c] = x1[c] = y1[c] = 1e30f; ar[c] = 0.0f; scr[c] = 0.0f;
      int p = c * 64 + lane;
      if (c < chunks && p < nv) {
        u64 k = skey[p];
        scr[c] = __uint_as_float((unsigned)(k >> 32));
        int n = NP - 1 - (int)(k & 0xFFFFull);
        int row = b * NP + n;
        float4 pr = *(const float4*)(props + (size_t)row * 4);
        float w = pr.z - pr.x, h = pr.w - pr.y;
        float cx = pr.x + 0.5f * w, cy = pr.y + 0.5f * h;
        float4 dd = *(const float4*)(deltas + (size_t)row * (NC * 4) + cls * 4);
        float dx = dd.x / 10.0f, dy = dd.y / 10.0f;
        float dw = fminf(dd.z / 5.0f, SCALE_CLAMP);
        float dh = fminf(dd.w / 5.0f, SCALE_CLAMP);
        float pcx = dx * w + cx, pcy = dy * h + cy;
        float pw = expf(dw) * w, ph = expf(dh) * h;
        x0[c] = clampf(pcx - 0.5f * pw, 0.0f, 1024.0f);
        y0[c] = clampf(pcy - 0.5f * ph, 0.0f, 1024.0f);
        x1[c] = clampf(pcx + 0.5f * pw, 0.0f, 1024.0f);
        y1[c] = clampf(pcy + 0.5f * ph, 0.0f, 1024.0f);
        ar[c] = (x1[c] - x0[c]) * (y1[c] - y0[c]);
      }
    }

    // precompute suppression rows (independent iterations -> pipelined)
    u64 rows_r[4][4];
    #pragma unroll
    for (int a = 0; a < 4; ++a)
      #pragma unroll
      for (int c2 = 0; c2 < 4; ++c2) rows_r[a][c2] = 0;

    for (int i = 0; i < nv; ++i) {
      int ci = i >> 6, bi = i & 63;
      float t0 = x0[0], t1 = y0[0], t2 = x1[0], t3 = y1[0], ta = ar[0];
      #pragma unroll
      for (int c = 1; c < 4; ++c)
        if (ci == c) { t0 = x0[c]; t1 = y0[c]; t2 = x1[c]; t3 = y1[c]; ta = ar[c]; }
      float ix0 = __shfl(t0, bi), iy0 = __shfl(t1, bi);
      float ix1 = __shfl(t2, bi), iy1 = __shfl(t3, bi);
      float ia  = __shfl(ta, bi);
      #pragma unroll
      for (int c2 = 0; c2 < 4; ++c2) if (c2 < chunks) {
        float iw = fmaxf(fminf(ix1, x1[c2]) - fmaxf(ix0, x0[c2]), 0.0f);
        float ih = fmaxf(fminf(iy1, y1[c2]) - fmaxf(iy0, y0[c2]), 0.0f);
        float inter = iw * ih;
        float iou = inter / (ia + ar[c2] - inter + 1e-9f);
        u64 mb = __ballot(iou > 0.5f);
        #pragma unroll
        for (int a = 0; a < 4; ++a)
          if (a == ci && lane == bi) rows_r[a][c2] = mb;
      }
    }

    // sequential greedy: shfl-broadcast precomputed rows
    u64 supm[4] = {0, 0, 0, 0}, keptm[4] = {0, 0, 0, 0};
    for (int i = 0; i < nv; ++i) {
      int ci = i >> 6, bi = i & 63;
      u64 sv = supm[0];
      #pragma unroll
      for (int c = 1; c < 4; ++c) if (ci == c) sv = supm[c];
      if ((sv >> bi) & 1ull) continue;
      #pragma unroll
      for (int c = 0; c < 4; ++c) if (ci == c) keptm[c] |= (1ull << bi);
      #pragma unroll
      for (int c2 = 0; c2 < 4; ++c2) if (c2 < chunks) {
        u64 rr = rows_r[0][c2];
        #pragma unroll
        for (int c = 1; c < 4; ++c) if (ci == c) rr = rows_r[c][c2];
        rr = __shfl(rr, bi);
        supm[c2] |= rr;
      }
    }

    // write-out: one atomic per block
    int total = 0;
    #pragma unroll
    for (int c = 0; c < 4; ++c) total += (int)__popcll(keptm[c]);
    int basei = 0;
    if (lane == 0 && total > 0) basei = atomicAdd(&ccnt[b], total);
    basei = __shfl(basei, 0);
    int prior = 0;
    #pragma unroll
    for (int c = 0; c < 4; ++c) if (c < chunks) {
      u64 mk = keptm[c];
      if ((mk >> lane) & 1ull) {
        int slot = basei + prior + (int)__popcll(mk & lt);
        if (slot < CAP) {
          int g = b * CAP + slot;
          cscore[g] = scr[c];
          cflat[g]  = j * NP + (c * 64 + lane);
          clabel[g] = cls;
          float4 bb; bb.x = x0[c]; bb.y = y0[c]; bb.z = x1[c]; bb.w = y1[c];
          *(float4*)(cbox + (size_t)g * 4) = bb;
        }
      }
      prior += (int)__popcll(mk);
    }
  } else if (nv > 256) {
    // ---- LDS fallback (rare) ----
    for (int c = 0; c < chunks; ++c) {
      int p = c * 64 + lane;
      if (p < nv) {
        u64 k = skey[p];
        int n = NP - 1 - (int)(k & 0xFFFFull);
        int row = b * NP + n;
        float4 pr = *(const float4*)(props + (size_t)row * 4);
        float w = pr.z - pr.x, h = pr.w - pr.y;
        float cx = pr.x + 0.5f * w, cy = pr.y + 0.5f * h;
        float4 dd = *(const float4*)(deltas + (size_t)row * (NC * 4) + cls * 4);
        float dx = dd.x / 10.0f, dy = dd.y / 10.0f;
        float dw = fminf(dd.z / 5.0f, SCALE_CLAMP);
        float dh = fminf(dd.w / 5.0f, SCALE_CLAMP);
        float pcx = dx * w + cx, pcy = dy * h + cy;
        float pw = expf(dw) * w, ph = expf(dh) * h;
        sbox[p][0] = clampf(pcx - 0.5f * pw, 0.0f, 1024.0f);
        sbox[p][1] = clampf(pcy - 0.5f * ph, 0.0f, 1024.0f);
        sbox[p][2] = clampf(pcx + 0.5f * pw, 0.0f, 1024.0f);
        sbox[p][3] = clampf(pcy + 0.5f * ph, 0.0f, 1024.0f);
      }
    }
    __syncthreads();
    unsigned int supbits = 0, keptbits = 0;
    for (int i = 0; i < nv; ++i) {
      int ci = i >> 6, bi = i & 63;
      u64 supmask = __ballot((supbits >> ci) & 1u);
      if ((supmask >> bi) & 1ull) continue;
      keptbits |= ((lane == bi) ? 1u : 0u) << ci;
      float bx1 = sbox[i][0], by1 = sbox[i][1], bx2 = sbox[i][2], by2 = sbox[i][3];
      float ai = (bx2 - bx1) * (by2 - by1);
      for (int c = 0; c < chunks; ++c) {
        int p = c * 64 + lane;
        float t1 = sbox[p][0], t2 = sbox[p][1], t3 = sbox[p][2], t4 = sbox[p][3];
        float at = (t3 - t1) * (t4 - t2);
        float iw = fmaxf(fminf(bx2, t3) - fmaxf(bx1, t1), 0.0f);
        float ih = fmaxf(fminf(by2, t4) - fmaxf(by1, t2), 0.0f);
        float inter = iw * ih;
        float iou = inter / (ai + at - inter + 1e-9f);
        bool s = (p < nv) && (iou > 0.5f);
        supbits |= (s ? 1u : 0u) << c;
      }
    }
    int total = 0;
    for (int c = 0; c < chunks; ++c)
      total += (int)__popcll(__ballot((keptbits >> c) & 1u));
    int basei = 0;
    if (lane == 0 && total > 0) basei = atomicAdd(&ccnt[b], total);
    basei = __shfl(basei, 0);
    int prior = 0;
    for (int c = 0; c < chunks; ++c) {
      u64 mask = __ballot((keptbits >> c) & 1u);
      if ((keptbits >> c) & 1u) {
        int slot = basei + prior + (int)__popcll(mask & lt);
        int p = c * 64 + lane;
        if (slot < CAP) {
          int g = b * CAP + slot;
          cscore[g] = __uint_as_float((unsigned)(skey[p] >> 32));
          cflat[g]  = j * NP + p;
          clabel[g] = cls;
          float4 bb; bb.x = sbox[p][0]; bb.y = sbox[p][1]; bb.z = sbox[p][2]; bb.w = sbox[p][3];
          *(float4*)(cbox + (size_t)g * 4) = bb;
        }
      }
      prior += (int)__popcll(mask);
    }
  }
}

// ---------------------------------------------------------------------------
// K3: per-image top-100, one wave per image. LDS histogram + wave suffix-scan
// threshold + u64-key exact rank sort (score desc, flat asc), direct scatter.
// ---------------------------------------------------------------------------
__global__ void __launch_bounds__(64)
topk_kernel(const float* __restrict__ cscore,
            const int* __restrict__ cflat,
            const int* __restrict__ clabel,
            const float* __restrict__ cbox,
            const int* __restrict__ ccnt,
            float* __restrict__ out) {
  int bb = blockIdx.x;
  int lane = threadIdx.x;
  u64 lt = (1ull << lane) - 1ull;
  int cnt = ccnt[bb]; if (cnt > CAP) cnt = CAP;
  const float* cs = cscore + (size_t)bb * CAP;
  const int* cf = cflat + (size_t)bb * CAP;

  __shared__ int hist[256];
  __shared__ u64 sel_k[MAXSEL];
  __shared__ int sel_i[MAXSEL];

  for (int i = lane; i < 256; i += 64) hist[i] = 0;
  __syncthreads();
  for (int i = lane; i < cnt; i += 64) {
    int bin = (int)(cs[i] * 256.0f);
    bin = bin < 0 ? 0 : (bin > 255 ? 255 : bin);
    atomicAdd(&hist[bin], 1);
  }
  __syncthreads();

  // threshold bin: largest t with |{bin >= t}| >= K (wave suffix scan, 4 bins/lane)
  int c0 = hist[lane * 4 + 0], c1 = hist[lane * 4 + 1];
  int c2 = hist[lane * 4 + 2], c3 = hist[lane * 4 + 3];
  int sl = c0 + c1 + c2 + c3;
  int suf = sl;
  #pragma unroll
  for (int off = 1; off < 64; off <<= 1) {
    int idx = lane + off;
    int v = __shfl(suf, idx < 64 ? idx : 63, 64);
    suf += (idx < 64) ? v : 0;
  }
  int basec = suf - sl;
  int f3 = basec + c3, f2 = f3 + c2, f1 = f2 + c1, f0 = f1 + c0;
  int best = -1;
  if (f3 >= KTOP) best = lane * 4 + 3;
  else if (f2 >= KTOP) best = lane * 4 + 2;
  else if (f1 >= KTOP) best = lane * 4 + 1;
  else if (f0 >= KTOP) best = lane * 4 + 0;
  #pragma unroll
  for (int off = 32; off; off >>= 1) {
    int o = __shfl_xor(best, off, 64);
    best = best > o ? best : o;
  }
  int thr = best < 0 ? 0 : best;

  // select candidates in bins >= thr (superset of top-K)
  int nsel = 0;
  for (int i0 = 0; i0 < cnt; i0 += 64) {
    int i = i0 + lane;
    bool pred = false; u64 key = 0;
    if (i < cnt) {
      float s_ = cs[i];
      int bin = (int)(s_ * 256.0f);
      bin = bin < 0 ? 0 : (bin > 255 ? 255 : bin);
      if (bin >= thr) {
        pred = true;
        key = ((u64)__float_as_uint(s_) << 32) | (unsigned)(65535 - cf[i]);
      }
    }
    u64 m = __ballot(pred);
    if (pred) {
      int pos = nsel + (int)__popcll(m & lt);
      if (pos < MAXSEL) { sel_k[pos] = key; sel_i[pos] = i; }
    }
    nsel += (int)__popcll(m);
  }
  if (nsel > MAXSEL) nsel = MAXSEL;
  __syncthreads();

  // exact rank sort + direct scatter
  for (int e = lane; e < nsel; e += 64) {
    u64 ke = sel_k[e];
    int r = 0;
    for (int m2 = 0; m2 < nsel; ++m2) r += (sel_k[m2] > ke) ? 1 : 0;
    if (r < KTOP) {
      int ci = sel_i[e];
      float4 bx = *(const float4*)(cbox + (size_t)(bb * CAP + ci) * 4);
      float* det = out + (size_t)(bb * KTOP + r) * 5;
      det[0] = bx.x; det[1] = bx.y; det[2] = bx.z; det[3] = bx.w;
      det[4] = __uint_as_float((unsigned)(ke >> 32));
      out[NB * KTOP * 5 + bb * KTOP + r] = (float)clabel[bb * CAP + ci];
    }
  }
  for (int k = nsel + lane; k < KTOP; k += 64) {
    float* det = out + (size_t)(bb * KTOP + k) * 5;
    det[0] = det[1] = det[2] = det[3] = 0.0f;
    det[4] = 0.0f;
    out[NB * KTOP * 5 + bb * KTOP + k] = 1.0f;  // zero-pad ties -> label 1
  }
}

// ---------------------------------------------------------------------------
extern "C" void kernel_launch(void* const* d_in, const int* in_sizes, int n_in,
                              void* d_out, int out_size, void* d_ws, size_t ws_size,
                              hipStream_t stream) {
  (void)in_sizes; (void)n_in; (void)out_size; (void)ws_size;
  const float* logits = (const float*)d_in[0];   // [B*N, C]
  const float* deltas = (const float*)d_in[1];   // [B*N, C*4]
  const float* props  = (const float*)d_in[2];   // [B, N, 4]
  float* out = (float*)d_out;

  float* wf       = (float*)d_ws;
  float* scores_t = wf;                          // 122880 floats
  float* cscore   = wf + 122880;                 // NB*CAP
  float* cbox     = wf + 163840;                 // NB*CAP*4 (16B aligned)
  int*   cflat    = (int*)(wf + 327680);
  int*   clabel   = (int*)(wf + 368640);
  int*   ccnt     = (int*)(wf + 409600);

  softmax_t_kernel<<<128, 256, 0, stream>>>(logits, scores_t, ccnt);
  nms_kernel<<<NB * NFG, 64, 0, stream>>>(scores_t, deltas, props,
                                          cscore, cflat, clabel, cbox, ccnt);
  topk_kernel<<<NB, 64, 0, stream>>>(cscore, cflat, clabel, cbox, ccnt, out);
}

// Round 7
// 139.358 us; speedup vs baseline: 1.4448x; 1.1753x over previous
//
#include <hip/hip_runtime.h>
#include <math.h>

// Problem constants (must match reference)
#define NB   2        // images
#define NP   1024     // proposals per image
#define NC   61       // classes incl. background
#define NFG  60       // foreground classes
#define KTOP 100      // detections per image
#define CAP  20480    // candidate buffer per image
#define MAXSEL 4096   // top-k selection buffer

typedef unsigned long long u64;

__device__ __forceinline__ float clampf(float x, float lo, float hi) {
  return fminf(fmaxf(x, lo), hi);
}

// ---------------------------------------------------------------------------
// K1: softmax + transpose. 128 blocks x 256 threads, 16 rows per block.
// Coalesced transposed writes via LDS tile (validated R5: FETCH 2753->1017 KB).
// ---------------------------------------------------------------------------
__global__ void __launch_bounds__(256)
softmax_t_kernel(const float* __restrict__ logits,
                 float* __restrict__ scores_t,
                 int* __restrict__ ccnt) {
  if (blockIdx.x == 0 && threadIdx.x < NB) ccnt[threadIdx.x] = 0;
  int b = blockIdx.x >> 6;          // 64 blocks per image
  int k = blockIdx.x & 63;          // tile (16 rows) within image
  int wave = threadIdx.x >> 6, lane = threadIdx.x & 63;
  __shared__ float p[16][65];       // +pad: phase-B reads hit distinct banks

  for (int rr = 0; rr < 4; ++rr) {
    int r = wave * 4 + rr;
    int row = b * NP + k * 16 + r;
    float x = (lane < NC) ? logits[(size_t)row * NC + lane] : -INFINITY;
    float m = x;
    #pragma unroll
    for (int o = 32; o; o >>= 1) m = fmaxf(m, __shfl_xor(m, o, 64));
    float e = (lane < NC) ? expf(x - m) : 0.0f;
    float s = e;
    #pragma unroll
    for (int o = 32; o; o >>= 1) s += __shfl_xor(s, o, 64);
    if (lane >= 1 && lane < NC) p[r][lane - 1] = e / s;   // fg classes only
  }
  __syncthreads();

  for (int idx = threadIdx.x; idx < NFG * 16; idx += 256) {
    int j = idx >> 4;
    int r = idx & 15;
    scores_t[(size_t)(b * NFG + j) * NP + k * 16 + r] = p[r][j];
  }
}

// ---------------------------------------------------------------------------
// Column-bitmask NMS fast path (CH = ceil(nv/64), compile-time).
// Lane t owns target entries {c*64+t}. colb[c][w] bit i (word w = i>>6) means
// "entry i suppresses my target c" — built in one all-pairs pass with a
// UNIFORM ds_read_b128 broadcast of box i (no bpermute, no per-iter ballot).
// The sequential greedy reconstructs row i with CH ballots per KEPT entry.
// ---------------------------------------------------------------------------
template<int CH>
__device__ __forceinline__ void
nms_fast(int b, int j, int cls, int lane, u64 lt, int nv,
         const u64* __restrict__ skey, float4* __restrict__ sbox4,
         const float* __restrict__ deltas, const float* __restrict__ props,
         float* __restrict__ cscore, int* __restrict__ cflat,
         int* __restrict__ clabel, float* __restrict__ cbox,
         int* __restrict__ ccnt) {
  const float SCALE_CLAMP = 4.135166556742356f;  // float(log(1000/16))
  float x0[CH], y0[CH], x1[CH], y1[CH], ar[CH], scr[CH];
  bool pv[CH];

  // decode own sorted entries; publish boxes to LDS (sorted order)
  #pragma unroll
  for (int c = 0; c < CH; ++c) {
    int p = c * 64 + lane;
    pv[c] = (p < nv);
    x0[c] = 1e30f; y0[c] = 1e30f; x1[c] = -1e30f; y1[c] = -1e30f;
    ar[c] = 0.0f; scr[c] = 0.0f;
    if (pv[c]) {
      u64 k = skey[p];
      scr[c] = __uint_as_float((unsigned)(k >> 32));
      int n = NP - 1 - (int)(k & 0xFFFFull);
      int row = b * NP + n;
      float4 pr = *(const float4*)(props + (size_t)row * 4);
      float w = pr.z - pr.x, h = pr.w - pr.y;
      float cx = pr.x + 0.5f * w, cy = pr.y + 0.5f * h;
      float4 dd = *(const float4*)(deltas + (size_t)row * (NC * 4) + cls * 4);
      float dx = dd.x / 10.0f, dy = dd.y / 10.0f;
      float dw = fminf(dd.z / 5.0f, SCALE_CLAMP);
      float dh = fminf(dd.w / 5.0f, SCALE_CLAMP);
      float pcx = dx * w + cx, pcy = dy * h + cy;
      float pw = expf(dw) * w, ph = expf(dh) * h;
      x0[c] = clampf(pcx - 0.5f * pw, 0.0f, 1024.0f);
      y0[c] = clampf(pcy - 0.5f * ph, 0.0f, 1024.0f);
      x1[c] = clampf(pcx + 0.5f * pw, 0.0f, 1024.0f);
      y1[c] = clampf(pcy + 0.5f * ph, 0.0f, 1024.0f);
      ar[c] = (x1[c] - x0[c]) * (y1[c] - y0[c]);
      float4 bb; bb.x = x0[c]; bb.y = y0[c]; bb.z = x1[c]; bb.w = y1[c];
      sbox4[p] = bb;
    }
  }
  __syncthreads();

  // all-pairs: build column bitmasks (pipelined: 1 uniform LDS load + VALU/iter)
  u64 colb[CH][CH];
  #pragma unroll
  for (int c = 0; c < CH; ++c)
    #pragma unroll
    for (int w = 0; w < CH; ++w) colb[c][w] = 0ull;

  for (int i = 0; i < nv; ++i) {
    float4 bi = sbox4[i];                       // uniform broadcast read
    float ia = (bi.z - bi.x) * (bi.w - bi.y);
    int wi = i >> 6, bp = i & 63;
    #pragma unroll
    for (int c = 0; c < CH; ++c) {
      float iw = fmaxf(fminf(bi.z, x1[c]) - fmaxf(bi.x, x0[c]), 0.0f);
      float ih = fmaxf(fminf(bi.w, y1[c]) - fmaxf(bi.y, y0[c]), 0.0f);
      float inter = iw * ih;
      float iou = inter / (ia + ar[c] - inter + 1e-9f);
      u64 add = (pv[c] && iou > 0.5f) ? (1ull << bp) : 0ull;
      #pragma unroll
      for (int w = 0; w < CH; ++w)
        colb[c][w] |= (w == wi) ? add : 0ull;
    }
  }

  // sequential greedy: wave-uniform sup/kept; CH ballots per kept entry
  u64 sup[CH], kept[CH];
  #pragma unroll
  for (int c = 0; c < CH; ++c) { sup[c] = 0ull; kept[c] = 0ull; }
  for (int i = 0; i < nv; ++i) {
    int wi = i >> 6, bp = i & 63;
    u64 sv = sup[0];
    #pragma unroll
    for (int w = 1; w < CH; ++w) sv = (w == wi) ? sup[w] : sv;
    if ((sv >> bp) & 1ull) continue;            // uniform branch
    #pragma unroll
    for (int w = 0; w < CH; ++w) kept[w] |= (w == wi) ? (1ull << bp) : 0ull;
    #pragma unroll
    for (int c = 0; c < CH; ++c) {
      u64 colsel = colb[c][0];
      #pragma unroll
      for (int w = 1; w < CH; ++w) colsel = (w == wi) ? colb[c][w] : colsel;
      u64 row = __ballot((int)((colsel >> bp) & 1ull));
      sup[c] |= row;
    }
  }

  // write-out: one atomic per block
  int total = 0;
  #pragma unroll
  for (int c = 0; c < CH; ++c) total += (int)__popcll(kept[c]);
  int basei = 0;
  if (lane == 0 && total > 0) basei = atomicAdd(&ccnt[b], total);
  basei = __shfl(basei, 0);
  int prior = 0;
  #pragma unroll
  for (int c = 0; c < CH; ++c) {
    u64 mk = kept[c];
    if ((mk >> lane) & 1ull) {
      int slot = basei + prior + (int)__popcll(mk & lt);
      if (slot < CAP) {
        int g = b * CAP + slot;
        cscore[g] = scr[c];
        cflat[g]  = j * NP + (c * 64 + lane);   // sorted position
        clabel[g] = cls;
        float4 bb; bb.x = x0[c]; bb.y = y0[c]; bb.z = x1[c]; bb.w = y1[c];
        *(float4*)(cbox + (size_t)g * 4) = bb;
      }
    }
    prior += (int)__popcll(mk);
  }
}

// ---------------------------------------------------------------------------
// K2: ONE WAVE per (image, fg class).
// ---------------------------------------------------------------------------
__global__ void __launch_bounds__(64)
nms_kernel(const float* __restrict__ scores_t,
           const float* __restrict__ deltas,
           const float* __restrict__ props,
           float* __restrict__ cscore,
           int* __restrict__ cflat,
           int* __restrict__ clabel,
           float* __restrict__ cbox,
           int* __restrict__ ccnt) {
  const float SCALE_CLAMP = 4.135166556742356f;
  int b = blockIdx.x / NFG, j = blockIdx.x % NFG, cls = j + 1;
  int lane = threadIdx.x;
  u64 lt = (1ull << lane) - 1ull;

  __shared__ u64 ukey[NP];
  __shared__ u64 skey[NP];
  __shared__ float4 sbox4[NP];

  // 1) coalesced score loads + ballot compaction
  const float* scol = scores_t + (size_t)(b * NFG + j) * NP;
  float sc[16];
  #pragma unroll
  for (int c = 0; c < 16; ++c) sc[c] = scol[c * 64 + lane];
  u64 msk[16];
  #pragma unroll
  for (int c = 0; c < 16; ++c) msk[c] = __ballot(sc[c] > 0.05f);
  int nv = 0;
  #pragma unroll
  for (int c = 0; c < 16; ++c) {
    if (sc[c] > 0.05f)
      ukey[nv + __popcll(msk[c] & lt)] =
          ((u64)__float_as_uint(sc[c]) << 32) | (unsigned)(NP - 1 - (c * 64 + lane));
    nv += (int)__popcll(msk[c]);
  }
  __syncthreads();
  if (nv == 0) return;
  int chunks = (nv + 63) >> 6;

  // 2) exact rank sort desc (keys unique: score bits | complemented index)
  for (int c = 0; c < chunks; ++c) {
    int e = c * 64 + lane;
    if (e < nv) {
      u64 ke = ukey[e];
      int r = 0;
      for (int m2 = 0; m2 < nv; ++m2) r += (ukey[m2] > ke) ? 1 : 0;
      skey[r] = ke;
    }
  }
  __syncthreads();

  // 3) NMS — templated column-bitmask fast paths
  if (nv <= 64) {
    nms_fast<1>(b, j, cls, lane, lt, nv, skey, sbox4, deltas, props,
                cscore, cflat, clabel, cbox, ccnt);
  } else if (nv <= 128) {
    nms_fast<2>(b, j, cls, lane, lt, nv, skey, sbox4, deltas, props,
                cscore, cflat, clabel, cbox, ccnt);
  } else if (nv <= 256) {
    nms_fast<4>(b, j, cls, lane, lt, nv, skey, sbox4, deltas, props,
                cscore, cflat, clabel, cbox, ccnt);
  } else {
    // ---- LDS fallback (never hit for this data; verified in R2) ----
    for (int c = 0; c < chunks; ++c) {
      int p = c * 64 + lane;
      if (p < nv) {
        u64 k = skey[p];
        int n = NP - 1 - (int)(k & 0xFFFFull);
        int row = b * NP + n;
        float4 pr = *(const float4*)(props + (size_t)row * 4);
        float w = pr.z - pr.x, h = pr.w - pr.y;
        float cx = pr.x + 0.5f * w, cy = pr.y + 0.5f * h;
        float4 dd = *(const float4*)(deltas + (size_t)row * (NC * 4) + cls * 4);
        float dx = dd.x / 10.0f, dy = dd.y / 10.0f;
        float dw = fminf(dd.z / 5.0f, SCALE_CLAMP);
        float dh = fminf(dd.w / 5.0f, SCALE_CLAMP);
        float pcx = dx * w + cx, pcy = dy * h + cy;
        float pw = expf(dw) * w, ph = expf(dh) * h;
        float4 bb;
        bb.x = clampf(pcx - 0.5f * pw, 0.0f, 1024.0f);
        bb.y = clampf(pcy - 0.5f * ph, 0.0f, 1024.0f);
        bb.z = clampf(pcx + 0.5f * pw, 0.0f, 1024.0f);
        bb.w = clampf(pcy + 0.5f * ph, 0.0f, 1024.0f);
        sbox4[p] = bb;
      }
    }
    __syncthreads();
    unsigned int supbits = 0, keptbits = 0;
    for (int i = 0; i < nv; ++i) {
      int ci = i >> 6, bi = i & 63;
      u64 supmask = __ballot((supbits >> ci) & 1u);
      if ((supmask >> bi) & 1ull) continue;
      keptbits |= ((lane == bi) ? 1u : 0u) << ci;
      float4 bx = sbox4[i];
      float ai = (bx.z - bx.x) * (bx.w - bx.y);
      for (int c = 0; c < chunks; ++c) {
        int p = c * 64 + lane;
        float4 tb = sbox4[p < nv ? p : 0];
        float at = (tb.z - tb.x) * (tb.w - tb.y);
        float iw = fmaxf(fminf(bx.z, tb.z) - fmaxf(bx.x, tb.x), 0.0f);
        float ih = fmaxf(fminf(bx.w, tb.w) - fmaxf(bx.y, tb.y), 0.0f);
        float inter = iw * ih;
        float iou = inter / (ai + at - inter + 1e-9f);
        bool s = (p < nv) && (iou > 0.5f);
        supbits |= (s ? 1u : 0u) << c;
      }
    }
    int total = 0;
    for (int c = 0; c < chunks; ++c)
      total += (int)__popcll(__ballot((keptbits >> c) & 1u));
    int basei = 0;
    if (lane == 0 && total > 0) basei = atomicAdd(&ccnt[b], total);
    basei = __shfl(basei, 0);
    int prior = 0;
    for (int c = 0; c < chunks; ++c) {
      u64 mask = __ballot((keptbits >> c) & 1u);
      if ((keptbits >> c) & 1u) {
        int slot = basei + prior + (int)__popcll(mask & lt);
        int p = c * 64 + lane;
        if (slot < CAP) {
          int g = b * CAP + slot;
          cscore[g] = __uint_as_float((unsigned)(skey[p] >> 32));
          cflat[g]  = j * NP + p;
          clabel[g] = cls;
          *(float4*)(cbox + (size_t)g * 4) = sbox4[p];
        }
      }
      prior += (int)__popcll(mask);
    }
  }
}

// ---------------------------------------------------------------------------
// K3: per-image top-100, one wave per image. LDS histogram + wave suffix-scan
// threshold + u64-key exact rank sort (score desc, flat asc), direct scatter.
// ---------------------------------------------------------------------------
__global__ void __launch_bounds__(64)
topk_kernel(const float* __restrict__ cscore,
            const int* __restrict__ cflat,
            const int* __restrict__ clabel,
            const float* __restrict__ cbox,
            const int* __restrict__ ccnt,
            float* __restrict__ out) {
  int bb = blockIdx.x;
  int lane = threadIdx.x;
  u64 lt = (1ull << lane) - 1ull;
  int cnt = ccnt[bb]; if (cnt > CAP) cnt = CAP;
  const float* cs = cscore + (size_t)bb * CAP;
  const int* cf = cflat + (size_t)bb * CAP;

  __shared__ int hist[256];
  __shared__ u64 sel_k[MAXSEL];
  __shared__ int sel_i[MAXSEL];

  for (int i = lane; i < 256; i += 64) hist[i] = 0;
  __syncthreads();
  for (int i = lane; i < cnt; i += 64) {
    int bin = (int)(cs[i] * 256.0f);
    bin = bin < 0 ? 0 : (bin > 255 ? 255 : bin);
    atomicAdd(&hist[bin], 1);
  }
  __syncthreads();

  int c0 = hist[lane * 4 + 0], c1 = hist[lane * 4 + 1];
  int c2 = hist[lane * 4 + 2], c3 = hist[lane * 4 + 3];
  int sl = c0 + c1 + c2 + c3;
  int suf = sl;
  #pragma unroll
  for (int off = 1; off < 64; off <<= 1) {
    int idx = lane + off;
    int v = __shfl(suf, idx < 64 ? idx : 63, 64);
    suf += (idx < 64) ? v : 0;
  }
  int basec = suf - sl;
  int f3 = basec + c3, f2 = f3 + c2, f1 = f2 + c1, f0 = f1 + c0;
  int best = -1;
  if (f3 >= KTOP) best = lane * 4 + 3;
  else if (f2 >= KTOP) best = lane * 4 + 2;
  else if (f1 >= KTOP) best = lane * 4 + 1;
  else if (f0 >= KTOP) best = lane * 4 + 0;
  #pragma unroll
  for (int off = 32; off; off >>= 1) {
    int o = __shfl_xor(best, off, 64);
    best = best > o ? best : o;
  }
  int thr = best < 0 ? 0 : best;

  int nsel = 0;
  for (int i0 = 0; i0 < cnt; i0 += 64) {
    int i = i0 + lane;
    bool pred = false; u64 key = 0;
    if (i < cnt) {
      float s_ = cs[i];
      int bin = (int)(s_ * 256.0f);
      bin = bin < 0 ? 0 : (bin > 255 ? 255 : bin);
      if (bin >= thr) {
        pred = true;
        key = ((u64)__float_as_uint(s_) << 32) | (unsigned)(65535 - cf[i]);
      }
    }
    u64 m = __ballot(pred);
    if (pred) {
      int pos = nsel + (int)__popcll(m & lt);
      if (pos < MAXSEL) { sel_k[pos] = key; sel_i[pos] = i; }
    }
    nsel += (int)__popcll(m);
  }
  if (nsel > MAXSEL) nsel = MAXSEL;
  __syncthreads();

  for (int e = lane; e < nsel; e += 64) {
    u64 ke = sel_k[e];
    int r = 0;
    for (int m2 = 0; m2 < nsel; ++m2) r += (sel_k[m2] > ke) ? 1 : 0;
    if (r < KTOP) {
      int ci = sel_i[e];
      float4 bx = *(const float4*)(cbox + (size_t)(bb * CAP + ci) * 4);
      float* det = out + (size_t)(bb * KTOP + r) * 5;
      det[0] = bx.x; det[1] = bx.y; det[2] = bx.z; det[3] = bx.w;
      det[4] = __uint_as_float((unsigned)(ke >> 32));
      out[NB * KTOP * 5 + bb * KTOP + r] = (float)clabel[bb * CAP + ci];
    }
  }
  for (int k = nsel + lane; k < KTOP; k += 64) {
    float* det = out + (size_t)(bb * KTOP + k) * 5;
    det[0] = det[1] = det[2] = det[3] = 0.0f;
    det[4] = 0.0f;
    out[NB * KTOP * 5 + bb * KTOP + k] = 1.0f;  // zero-pad ties -> label 1
  }
}

// ---------------------------------------------------------------------------
extern "C" void kernel_launch(void* const* d_in, const int* in_sizes, int n_in,
                              void* d_out, int out_size, void* d_ws, size_t ws_size,
                              hipStream_t stream) {
  (void)in_sizes; (void)n_in; (void)out_size; (void)ws_size;
  const float* logits = (const float*)d_in[0];   // [B*N, C]
  const float* deltas = (const float*)d_in[1];   // [B*N, C*4]
  const float* props  = (const float*)d_in[2];   // [B, N, 4]
  float* out = (float*)d_out;

  float* wf       = (float*)d_ws;
  float* scores_t = wf;                          // 122880 floats
  float* cscore   = wf + 122880;                 // NB*CAP
  float* cbox     = wf + 163840;                 // NB*CAP*4 (16B aligned)
  int*   cflat    = (int*)(wf + 327680);
  int*   clabel   = (int*)(wf + 368640);
  int*   ccnt     = (int*)(wf + 409600);

  softmax_t_kernel<<<128, 256, 0, stream>>>(logits, scores_t, ccnt);
  nms_kernel<<<NB * NFG, 64, 0, stream>>>(scores_t, deltas, props,
                                          cscore, cflat, clabel, cbox, ccnt);
  topk_kernel<<<NB, 64, 0, stream>>>(cscore, cflat, clabel, cbox, ccnt, out);
}

// Round 8
// 106.652 us; speedup vs baseline: 1.8879x; 1.3067x over previous
//
#include <hip/hip_runtime.h>
#include <math.h>

// Problem constants (must match reference)
#define NB   2        // images
#define NP   1024     // proposals per image
#define NC   61       // classes incl. background
#define NFG  60       // foreground classes
#define KTOP 100      // detections per image
#define CAP  20480    // candidate buffer per image
#define MAXSEL 4096   // top-k selection buffer

typedef unsigned long long u64;

__device__ __forceinline__ float clampf(float x, float lo, float hi) {
  return fminf(fmaxf(x, lo), hi);
}

// ---------------------------------------------------------------------------
// K1: softmax + transpose. 128 blocks x 256 threads, 16 rows per block.
// Coalesced transposed writes via LDS tile (validated R5: FETCH 2753->1017 KB).
// ---------------------------------------------------------------------------
__global__ void __launch_bounds__(256)
softmax_t_kernel(const float* __restrict__ logits,
                 float* __restrict__ scores_t,
                 int* __restrict__ ccnt) {
  if (blockIdx.x == 0 && threadIdx.x < NB) ccnt[threadIdx.x] = 0;
  int b = blockIdx.x >> 6;          // 64 blocks per image
  int k = blockIdx.x & 63;          // tile (16 rows) within image
  int wave = threadIdx.x >> 6, lane = threadIdx.x & 63;
  __shared__ float p[16][65];       // +pad: phase-B reads hit distinct banks

  for (int rr = 0; rr < 4; ++rr) {
    int r = wave * 4 + rr;
    int row = b * NP + k * 16 + r;
    float x = (lane < NC) ? logits[(size_t)row * NC + lane] : -INFINITY;
    float m = x;
    #pragma unroll
    for (int o = 32; o; o >>= 1) m = fmaxf(m, __shfl_xor(m, o, 64));
    float e = (lane < NC) ? expf(x - m) : 0.0f;
    float s = e;
    #pragma unroll
    for (int o = 32; o; o >>= 1) s += __shfl_xor(s, o, 64);
    if (lane >= 1 && lane < NC) p[r][lane - 1] = e / s;   // fg classes only
  }
  __syncthreads();

  for (int idx = threadIdx.x; idx < NFG * 16; idx += 256) {
    int j = idx >> 4;
    int r = idx & 15;
    scores_t[(size_t)(b * NFG + j) * NP + k * 16 + r] = p[r][j];
  }
}

// ---------------------------------------------------------------------------
// Column-bitmask NMS fast path (CH = ceil(nv/64), compile-time).
// (Validated R7: nms_kernel dropped from 59.4 us to below the top-5.)
// ---------------------------------------------------------------------------
template<int CH>
__device__ __forceinline__ void
nms_fast(int b, int j, int cls, int lane, u64 lt, int nv,
         const u64* __restrict__ skey, float4* __restrict__ sbox4,
         const float* __restrict__ deltas, const float* __restrict__ props,
         float* __restrict__ cscore, int* __restrict__ cflat,
         int* __restrict__ clabel, float* __restrict__ cbox,
         int* __restrict__ ccnt) {
  const float SCALE_CLAMP = 4.135166556742356f;  // float(log(1000/16))
  float x0[CH], y0[CH], x1[CH], y1[CH], ar[CH], scr[CH];
  bool pv[CH];

  #pragma unroll
  for (int c = 0; c < CH; ++c) {
    int p = c * 64 + lane;
    pv[c] = (p < nv);
    x0[c] = 1e30f; y0[c] = 1e30f; x1[c] = -1e30f; y1[c] = -1e30f;
    ar[c] = 0.0f; scr[c] = 0.0f;
    if (pv[c]) {
      u64 k = skey[p];
      scr[c] = __uint_as_float((unsigned)(k >> 32));
      int n = NP - 1 - (int)(k & 0xFFFFull);
      int row = b * NP + n;
      float4 pr = *(const float4*)(props + (size_t)row * 4);
      float w = pr.z - pr.x, h = pr.w - pr.y;
      float cx = pr.x + 0.5f * w, cy = pr.y + 0.5f * h;
      float4 dd = *(const float4*)(deltas + (size_t)row * (NC * 4) + cls * 4);
      float dx = dd.x / 10.0f, dy = dd.y / 10.0f;
      float dw = fminf(dd.z / 5.0f, SCALE_CLAMP);
      float dh = fminf(dd.w / 5.0f, SCALE_CLAMP);
      float pcx = dx * w + cx, pcy = dy * h + cy;
      float pw = expf(dw) * w, ph = expf(dh) * h;
      x0[c] = clampf(pcx - 0.5f * pw, 0.0f, 1024.0f);
      y0[c] = clampf(pcy - 0.5f * ph, 0.0f, 1024.0f);
      x1[c] = clampf(pcx + 0.5f * pw, 0.0f, 1024.0f);
      y1[c] = clampf(pcy + 0.5f * ph, 0.0f, 1024.0f);
      ar[c] = (x1[c] - x0[c]) * (y1[c] - y0[c]);
      float4 bb; bb.x = x0[c]; bb.y = y0[c]; bb.z = x1[c]; bb.w = y1[c];
      sbox4[p] = bb;
    }
  }
  __syncthreads();

  // all-pairs: build column bitmasks (pipelined: 1 uniform LDS load + VALU/iter)
  u64 colb[CH][CH];
  #pragma unroll
  for (int c = 0; c < CH; ++c)
    #pragma unroll
    for (int w = 0; w < CH; ++w) colb[c][w] = 0ull;

  for (int i = 0; i < nv; ++i) {
    float4 bi = sbox4[i];                       // uniform broadcast read
    float ia = (bi.z - bi.x) * (bi.w - bi.y);
    int wi = i >> 6, bp = i & 63;
    #pragma unroll
    for (int c = 0; c < CH; ++c) {
      float iw = fmaxf(fminf(bi.z, x1[c]) - fmaxf(bi.x, x0[c]), 0.0f);
      float ih = fmaxf(fminf(bi.w, y1[c]) - fmaxf(bi.y, y0[c]), 0.0f);
      float inter = iw * ih;
      float iou = inter / (ia + ar[c] - inter + 1e-9f);
      u64 add = (pv[c] && iou > 0.5f) ? (1ull << bp) : 0ull;
      #pragma unroll
      for (int w = 0; w < CH; ++w)
        colb[c][w] |= (w == wi) ? add : 0ull;
    }
  }

  // sequential greedy: wave-uniform sup/kept; CH ballots per kept entry
  u64 sup[CH], kept[CH];
  #pragma unroll
  for (int c = 0; c < CH; ++c) { sup[c] = 0ull; kept[c] = 0ull; }
  for (int i = 0; i < nv; ++i) {
    int wi = i >> 6, bp = i & 63;
    u64 sv = sup[0];
    #pragma unroll
    for (int w = 1; w < CH; ++w) sv = (w == wi) ? sup[w] : sv;
    if ((sv >> bp) & 1ull) continue;            // uniform branch
    #pragma unroll
    for (int w = 0; w < CH; ++w) kept[w] |= (w == wi) ? (1ull << bp) : 0ull;
    #pragma unroll
    for (int c = 0; c < CH; ++c) {
      u64 colsel = colb[c][0];
      #pragma unroll
      for (int w = 1; w < CH; ++w) colsel = (w == wi) ? colb[c][w] : colsel;
      u64 row = __ballot((int)((colsel >> bp) & 1ull));
      sup[c] |= row;
    }
  }

  // write-out: one atomic per block
  int total = 0;
  #pragma unroll
  for (int c = 0; c < CH; ++c) total += (int)__popcll(kept[c]);
  int basei = 0;
  if (lane == 0 && total > 0) basei = atomicAdd(&ccnt[b], total);
  basei = __shfl(basei, 0);
  int prior = 0;
  #pragma unroll
  for (int c = 0; c < CH; ++c) {
    u64 mk = kept[c];
    if ((mk >> lane) & 1ull) {
      int slot = basei + prior + (int)__popcll(mk & lt);
      if (slot < CAP) {
        int g = b * CAP + slot;
        cscore[g] = scr[c];
        cflat[g]  = j * NP + (c * 64 + lane);   // sorted position
        clabel[g] = cls;
        float4 bb; bb.x = x0[c]; bb.y = y0[c]; bb.z = x1[c]; bb.w = y1[c];
        *(float4*)(cbox + (size_t)g * 4) = bb;
      }
    }
    prior += (int)__popcll(mk);
  }
}

// ---------------------------------------------------------------------------
// K2: ONE WAVE per (image, fg class).
// ---------------------------------------------------------------------------
__global__ void __launch_bounds__(64)
nms_kernel(const float* __restrict__ scores_t,
           const float* __restrict__ deltas,
           const float* __restrict__ props,
           float* __restrict__ cscore,
           int* __restrict__ cflat,
           int* __restrict__ clabel,
           float* __restrict__ cbox,
           int* __restrict__ ccnt) {
  const float SCALE_CLAMP = 4.135166556742356f;
  int b = blockIdx.x / NFG, j = blockIdx.x % NFG, cls = j + 1;
  int lane = threadIdx.x;
  u64 lt = (1ull << lane) - 1ull;

  __shared__ u64 ukey[NP];
  __shared__ u64 skey[NP];
  __shared__ float4 sbox4[NP];

  // 1) coalesced score loads + ballot compaction
  const float* scol = scores_t + (size_t)(b * NFG + j) * NP;
  float sc[16];
  #pragma unroll
  for (int c = 0; c < 16; ++c) sc[c] = scol[c * 64 + lane];
  u64 msk[16];
  #pragma unroll
  for (int c = 0; c < 16; ++c) msk[c] = __ballot(sc[c] > 0.05f);
  int nv = 0;
  #pragma unroll
  for (int c = 0; c < 16; ++c) {
    if (sc[c] > 0.05f)
      ukey[nv + __popcll(msk[c] & lt)] =
          ((u64)__float_as_uint(sc[c]) << 32) | (unsigned)(NP - 1 - (c * 64 + lane));
    nv += (int)__popcll(msk[c]);
  }
  __syncthreads();
  if (nv == 0) return;
  int chunks = (nv + 63) >> 6;

  // 2) exact rank sort desc (keys unique: score bits | complemented index)
  for (int c = 0; c < chunks; ++c) {
    int e = c * 64 + lane;
    if (e < nv) {
      u64 ke = ukey[e];
      int r = 0;
      for (int m2 = 0; m2 < nv; ++m2) r += (ukey[m2] > ke) ? 1 : 0;
      skey[r] = ke;
    }
  }
  __syncthreads();

  // 3) NMS — templated column-bitmask fast paths
  if (nv <= 64) {
    nms_fast<1>(b, j, cls, lane, lt, nv, skey, sbox4, deltas, props,
                cscore, cflat, clabel, cbox, ccnt);
  } else if (nv <= 128) {
    nms_fast<2>(b, j, cls, lane, lt, nv, skey, sbox4, deltas, props,
                cscore, cflat, clabel, cbox, ccnt);
  } else if (nv <= 256) {
    nms_fast<4>(b, j, cls, lane, lt, nv, skey, sbox4, deltas, props,
                cscore, cflat, clabel, cbox, ccnt);
  } else {
    // ---- LDS fallback (never hit for this data; verified in R2) ----
    for (int c = 0; c < chunks; ++c) {
      int p = c * 64 + lane;
      if (p < nv) {
        u64 k = skey[p];
        int n = NP - 1 - (int)(k & 0xFFFFull);
        int row = b * NP + n;
        float4 pr = *(const float4*)(props + (size_t)row * 4);
        float w = pr.z - pr.x, h = pr.w - pr.y;
        float cx = pr.x + 0.5f * w, cy = pr.y + 0.5f * h;
        float4 dd = *(const float4*)(deltas + (size_t)row * (NC * 4) + cls * 4);
        float dx = dd.x / 10.0f, dy = dd.y / 10.0f;
        float dw = fminf(dd.z / 5.0f, SCALE_CLAMP);
        float dh = fminf(dd.w / 5.0f, SCALE_CLAMP);
        float pcx = dx * w + cx, pcy = dy * h + cy;
        float pw = expf(dw) * w, ph = expf(dh) * h;
        float4 bb;
        bb.x = clampf(pcx - 0.5f * pw, 0.0f, 1024.0f);
        bb.y = clampf(pcy - 0.5f * ph, 0.0f, 1024.0f);
        bb.z = clampf(pcx + 0.5f * pw, 0.0f, 1024.0f);
        bb.w = clampf(pcy + 0.5f * ph, 0.0f, 1024.0f);
        sbox4[p] = bb;
      }
    }
    __syncthreads();
    unsigned int supbits = 0, keptbits = 0;
    for (int i = 0; i < nv; ++i) {
      int ci = i >> 6, bi = i & 63;
      u64 supmask = __ballot((supbits >> ci) & 1u);
      if ((supmask >> bi) & 1ull) continue;
      keptbits |= ((lane == bi) ? 1u : 0u) << ci;
      float4 bx = sbox4[i];
      float ai = (bx.z - bx.x) * (bx.w - bx.y);
      for (int c = 0; c < chunks; ++c) {
        int p = c * 64 + lane;
        float4 tb = sbox4[p < nv ? p : 0];
        float at = (tb.z - tb.x) * (tb.w - tb.y);
        float iw = fmaxf(fminf(bx.z, tb.z) - fmaxf(bx.x, tb.x), 0.0f);
        float ih = fmaxf(fminf(bx.w, tb.w) - fmaxf(bx.y, tb.y), 0.0f);
        float inter = iw * ih;
        float iou = inter / (ai + at - inter + 1e-9f);
        bool s = (p < nv) && (iou > 0.5f);
        supbits |= (s ? 1u : 0u) << c;
      }
    }
    int total = 0;
    for (int c = 0; c < chunks; ++c)
      total += (int)__popcll(__ballot((keptbits >> c) & 1u));
    int basei = 0;
    if (lane == 0 && total > 0) basei = atomicAdd(&ccnt[b], total);
    basei = __shfl(basei, 0);
    int prior = 0;
    for (int c = 0; c < chunks; ++c) {
      u64 mask = __ballot((keptbits >> c) & 1u);
      if ((keptbits >> c) & 1u) {
        int slot = basei + prior + (int)__popcll(mask & lt);
        int p = c * 64 + lane;
        if (slot < CAP) {
          int g = b * CAP + slot;
          cscore[g] = __uint_as_float((unsigned)(skey[p] >> 32));
          cflat[g]  = j * NP + p;
          clabel[g] = cls;
          *(float4*)(cbox + (size_t)g * 4) = sbox4[p];
        }
      }
      prior += (int)__popcll(mask);
    }
  }
}

// ---------------------------------------------------------------------------
// K3: per-image top-100, 256 threads (4 waves) per image.
// float4/int4 vectorized scans (cnt~3300 -> ~3 iterations instead of 52),
// cross-wave compaction via wave prefix-sum + one LDS atomic per wave.
// ---------------------------------------------------------------------------
__global__ void __launch_bounds__(256)
topk_kernel(const float* __restrict__ cscore,
            const int* __restrict__ cflat,
            const int* __restrict__ clabel,
            const float* __restrict__ cbox,
            const int* __restrict__ ccnt,
            float* __restrict__ out) {
  int bb = blockIdx.x;
  int tid = threadIdx.x;
  int lane = tid & 63;
  int cnt = ccnt[bb]; if (cnt > CAP) cnt = CAP;
  const float* cs = cscore + (size_t)bb * CAP;
  const int* cf = cflat + (size_t)bb * CAP;

  __shared__ int hist[256];
  __shared__ u64 sel_k[MAXSEL];
  __shared__ int sel_i[MAXSEL];
  __shared__ int s_thr, s_sel;

  hist[tid] = 0;
  if (tid == 0) s_sel = 0;
  __syncthreads();

  // ---- histogram pass: 4 consecutive floats per thread (16B/lane) ----
  for (int i0 = tid * 4; i0 < cnt; i0 += 1024) {
    if (i0 + 3 < cnt) {
      float4 v = *(const float4*)(cs + i0);
      int b0 = min(max((int)(v.x * 256.0f), 0), 255);
      int b1 = min(max((int)(v.y * 256.0f), 0), 255);
      int b2 = min(max((int)(v.z * 256.0f), 0), 255);
      int b3 = min(max((int)(v.w * 256.0f), 0), 255);
      atomicAdd(&hist[b0], 1); atomicAdd(&hist[b1], 1);
      atomicAdd(&hist[b2], 1); atomicAdd(&hist[b3], 1);
    } else {
      for (int k = 0; k < 4 && i0 + k < cnt; ++k) {
        int bin = min(max((int)(cs[i0 + k] * 256.0f), 0), 255);
        atomicAdd(&hist[bin], 1);
      }
    }
  }
  __syncthreads();

  // ---- threshold bin via wave-0 suffix scan (4 bins/lane) ----
  if (tid < 64) {
    int c0 = hist[lane * 4 + 0], c1 = hist[lane * 4 + 1];
    int c2 = hist[lane * 4 + 2], c3 = hist[lane * 4 + 3];
    int sl = c0 + c1 + c2 + c3;
    int suf = sl;
    #pragma unroll
    for (int off = 1; off < 64; off <<= 1) {
      int idx = lane + off;
      int v = __shfl(suf, idx < 64 ? idx : 63, 64);
      suf += (idx < 64) ? v : 0;
    }
    int basec = suf - sl;
    int f3 = basec + c3, f2 = f3 + c2, f1 = f2 + c1, f0 = f1 + c0;
    int best = -1;
    if (f3 >= KTOP) best = lane * 4 + 3;
    else if (f2 >= KTOP) best = lane * 4 + 2;
    else if (f1 >= KTOP) best = lane * 4 + 1;
    else if (f0 >= KTOP) best = lane * 4 + 0;
    #pragma unroll
    for (int off = 32; off; off >>= 1) {
      int o = __shfl_xor(best, off, 64);
      best = best > o ? best : o;
    }
    if (lane == 0) s_thr = best < 0 ? 0 : best;
  }
  __syncthreads();
  int thr = s_thr;

  // ---- selection pass: 4/thread, wave prefix-sum compaction ----
  for (int i0 = tid * 4; i0 < cnt + 1023; i0 += 1024) {
    // (loop bound uniform across block: every thread executes same #iters)
    float v[4]; int fl[4]; bool sel[4];
    int ct = 0;
    bool full = (i0 + 3 < cnt);
    if (full) {
      float4 vv = *(const float4*)(cs + i0);
      int4 ff = *(const int4*)(cf + i0);
      v[0] = vv.x; v[1] = vv.y; v[2] = vv.z; v[3] = vv.w;
      fl[0] = ff.x; fl[1] = ff.y; fl[2] = ff.z; fl[3] = ff.w;
    } else {
      for (int k = 0; k < 4; ++k) {
        int i = i0 + k;
        v[k] = (i < cnt) ? cs[i] : -1.0f;
        fl[k] = (i < cnt) ? cf[i] : 0;
      }
    }
    #pragma unroll
    for (int k = 0; k < 4; ++k) {
      int bin = min(max((int)(v[k] * 256.0f), 0), 255);
      sel[k] = (i0 + k < cnt) && (v[k] > 0.0f) && (bin >= thr);
      ct += sel[k] ? 1 : 0;
    }
    // wave-inclusive scan of ct
    int scan = ct;
    #pragma unroll
    for (int off = 1; off < 64; off <<= 1) {
      int vv2 = __shfl_up(scan, off, 64);
      if (lane >= off) scan += vv2;
    }
    int excl = scan - ct;
    int wtotal = __shfl(scan, 63, 64);
    int wbase = 0;
    if (lane == 63 && wtotal > 0) wbase = atomicAdd(&s_sel, wtotal);
    wbase = __shfl(wbase, 63, 64);
    int pos = wbase + excl;
    #pragma unroll
    for (int k = 0; k < 4; ++k) {
      if (sel[k] && pos < MAXSEL) {
        sel_k[pos] = ((u64)__float_as_uint(v[k]) << 32) | (unsigned)(65535 - fl[k]);
        sel_i[pos] = i0 + k;
        ++pos;
      } else if (sel[k]) {
        ++pos;
      }
    }
  }
  __syncthreads();
  int nsel = s_sel < MAXSEL ? s_sel : MAXSEL;

  // ---- exact rank sort (score desc, flat asc) + direct scatter ----
  for (int e = tid; e < nsel; e += 256) {
    u64 ke = sel_k[e];
    int r = 0;
    for (int m2 = 0; m2 < nsel; ++m2) r += (sel_k[m2] > ke) ? 1 : 0;
    if (r < KTOP) {
      int ci = sel_i[e];
      float4 bx = *(const float4*)(cbox + (size_t)(bb * CAP + ci) * 4);
      float* det = out + (size_t)(bb * KTOP + r) * 5;
      det[0] = bx.x; det[1] = bx.y; det[2] = bx.z; det[3] = bx.w;
      det[4] = __uint_as_float((unsigned)(ke >> 32));
      out[NB * KTOP * 5 + bb * KTOP + r] = (float)clabel[bb * CAP + ci];
    }
  }
  for (int k = nsel + tid; k < KTOP; k += 256) {
    float* det = out + (size_t)(bb * KTOP + k) * 5;
    det[0] = det[1] = det[2] = det[3] = 0.0f;
    det[4] = 0.0f;
    out[NB * KTOP * 5 + bb * KTOP + k] = 1.0f;  // zero-pad ties -> label 1
  }
}

// ---------------------------------------------------------------------------
extern "C" void kernel_launch(void* const* d_in, const int* in_sizes, int n_in,
                              void* d_out, int out_size, void* d_ws, size_t ws_size,
                              hipStream_t stream) {
  (void)in_sizes; (void)n_in; (void)out_size; (void)ws_size;
  const float* logits = (const float*)d_in[0];   // [B*N, C]
  const float* deltas = (const float*)d_in[1];   // [B*N, C*4]
  const float* props  = (const float*)d_in[2];   // [B, N, 4]
  float* out = (float*)d_out;

  float* wf       = (float*)d_ws;
  float* scores_t = wf;                          // 122880 floats
  float* cscore   = wf + 122880;                 // NB*CAP
  float* cbox     = wf + 163840;                 // NB*CAP*4 (16B aligned)
  int*   cflat    = (int*)(wf + 327680);
  int*   clabel   = (int*)(wf + 368640);
  int*   ccnt     = (int*)(wf + 409600);

  softmax_t_kernel<<<128, 256, 0, stream>>>(logits, scores_t, ccnt);
  nms_kernel<<<NB * NFG, 64, 0, stream>>>(scores_t, deltas, props,
                                          cscore, cflat, clabel, cbox, ccnt);
  topk_kernel<<<NB, 256, 0, stream>>>(cscore, cflat, clabel, cbox, ccnt, out);
}